// Round 2
// baseline (629.475 us; speedup 1.0000x reference)
//
#include <hip/hip_runtime.h>

// DenseGrid trilinear interpolation, MI355X.
// R4: fine-grained sort + LDS-staged interpolation.
// R3 showed k_main is no longer HBM-bytes-bound (3.17 TB/s on mostly-cached
// traffic) but scattered-request-bound: 72 independent 8B gathers per point.
// Fix: bin points by (iz0, iy0) -> 16K bins. Each bin's codebook footprint is
// exactly 4 rows x 128 x 18 floats = 36 KB -> fits LDS. One block per bin:
// coalesced dwordx4 staging of the 4 rows, then all corner reads are LDS.
// Per-point math is the identical fma chain -> bit-identical results.
//
// Pipeline: k_zero -> k_hist (global atomics) -> k_scan -> k_scatter -> k_main.
// Fallback to the R2 single-kernel path if workspace is too small.

constexpr int RES = 128;
constexpr int NB2 = 128 * 128;      // bins: (iz0 << 7) | iy0
constexpr int TPB = 576;            // main kernel: 9 threads/point, 64 pts/chunk
constexpr int PPB = TPB / 9;
constexpr int ROWF = 128 * 18;      // floats per codebook row (one y,z line over x)

typedef float vf2 __attribute__((ext_vector_type(2)));
typedef float vf4 __attribute__((ext_vector_type(4)));

struct Xf {
    float m00, m01, m02, m10, m11, m12, m20, m21, m22;
    float tx, ty, tz;
};

__device__ __forceinline__ Xf load_xf(const float* __restrict__ tr) {
    Xf X;
    const float a = tr[0], b = tr[1],  c = tr[2];
    const float d = tr[4], e = tr[5],  g = tr[6];
    const float h = tr[8], i = tr[9],  j = tr[10];
    X.tx = tr[3]; X.ty = tr[7]; X.tz = tr[11];
    const float det = a*(e*j - g*i) - b*(d*j - g*h) + c*(d*i - e*h);
    const float rd  = 1.0f / det;
    X.m00 = (e*j - g*i) * rd; X.m01 = (c*i - b*j) * rd; X.m02 = (b*g - c*e) * rd;
    X.m10 = (g*h - d*j) * rd; X.m11 = (a*j - c*h) * rd; X.m12 = (c*d - a*g) * rd;
    X.m20 = (d*i - e*h) * rd; X.m21 = (b*h - a*i) * rd; X.m22 = (a*e - b*d) * rd;
    return X;
}

// Explicit fma chain so bin computation is bit-identical across kernels.
__device__ __forceinline__ float qcoord(float m0, float m1, float m2,
                                        float x, float y, float z) {
    return __fmaf_rn(m0, x, __fmaf_rn(m1, y, m2 * z)) * (float)(RES - 1);
}

__device__ __forceinline__ int bin_of_qyz(float qy, float qz) {
    const int iy0 = min(max((int)floorf(qy), 0), RES - 1);
    const int iz0 = min(max((int)floorf(qz), 0), RES - 1);
    return (iz0 << 7) | iy0;
}

__global__ __launch_bounds__(256)
void k_zero(unsigned* __restrict__ hist) {
    const int i = blockIdx.x * 256 + threadIdx.x;
    if (i < NB2) hist[i] = 0u;
}

__global__ __launch_bounds__(256)
void k_hist(const float* __restrict__ pts, const float* __restrict__ tr,
            unsigned* __restrict__ hist, int npts)
{
    const int p = blockIdx.x * 256 + threadIdx.x;
    if (p >= npts) return;
    const Xf X = load_xf(tr);
    const float x = pts[p*3 + 0] - X.tx;
    const float y = pts[p*3 + 1] - X.ty;
    const float z = pts[p*3 + 2] - X.tz;
    const float qy = qcoord(X.m10, X.m11, X.m12, x, y, z);
    const float qz = qcoord(X.m20, X.m21, X.m22, x, y, z);
    atomicAdd(&hist[bin_of_qyz(qy, qz)], 1u);
}

__global__ __launch_bounds__(1024)
void k_scan(const unsigned* __restrict__ hist,
            unsigned* __restrict__ base, unsigned* __restrict__ cursor)
{
    __shared__ unsigned s[1024];
    const int t = threadIdx.x;
    unsigned carry = 0u;
    for (int c = 0; c < NB2 / 1024; ++c) {
        const int i = c * 1024 + t;
        const unsigned v = hist[i];
        s[t] = v;
        __syncthreads();
        for (int off = 1; off < 1024; off <<= 1) {
            const unsigned tmp = (t >= off) ? s[t - off] : 0u;
            __syncthreads();
            s[t] += tmp;
            __syncthreads();
        }
        const unsigned excl = s[t] - v + carry;
        base[i]   = excl;
        cursor[i] = excl;
        const unsigned tot = s[1023];
        __syncthreads();
        carry += tot;
    }
}

__global__ __launch_bounds__(256)
void k_scatter(const float* __restrict__ pts, const float* __restrict__ tr,
               unsigned* __restrict__ cursor, vf4* __restrict__ rec, int npts)
{
    const int p = blockIdx.x * 256 + threadIdx.x;
    if (p >= npts) return;
    const Xf X = load_xf(tr);
    const float x = pts[p*3 + 0] - X.tx;
    const float y = pts[p*3 + 1] - X.ty;
    const float z = pts[p*3 + 2] - X.tz;
    const float qx = qcoord(X.m00, X.m01, X.m02, x, y, z);
    const float qy = qcoord(X.m10, X.m11, X.m12, x, y, z);
    const float qz = qcoord(X.m20, X.m21, X.m22, x, y, z);
    const int bn = bin_of_qyz(qy, qz);
    unsigned pos = atomicAdd(&cursor[bn], 1u);
    if (pos >= (unsigned)npts) pos = (unsigned)npts - 1u;   // insurance only
    vf4 v; v.x = qx; v.y = qy; v.z = qz; v.w = __int_as_float(p);
    rec[pos] = v;
}

__global__ __launch_bounds__(TPB)
void k_main(const vf4* __restrict__ rec, const unsigned* __restrict__ hist,
            const unsigned* __restrict__ base, const float* __restrict__ cb,
            float* __restrict__ out)
{
    const int b = blockIdx.x;
    const unsigned n = hist[b];
    if (n == 0u) return;
    const unsigned bs = base[b];

    const int iy0 = b & 127, iz0 = b >> 7;
    const int iy1 = min(iy0 + 1, RES - 1), iz1 = min(iz0 + 1, RES - 1);

    // LDS: 4 codebook rows (c = dy + 2*dz), each 128 cells x 18 floats.
    __shared__ float sld[4 * ROWF];          // 36864 B
    __shared__ vf4   srec[PPB];

    const int t = threadIdx.x;
    {
        const int ry[4] = { iy0, iy1, iy0, iy1 };
        const int rz[4] = { iz0, iz0, iz1, iz1 };
        #pragma unroll
        for (int c = 0; c < 4; ++c) {
            const vf4* src =
                reinterpret_cast<const vf4*>(cb + (size_t)((rz[c] << 14) | (ry[c] << 7)) * 18);
            reinterpret_cast<vf4*>(&sld[c * ROWF])[t] = src[t];   // 576 x 16 B = one row
        }
    }

    const int pl = t / 9;
    const int f  = t - pl * 9;

    for (unsigned off = 0; off < n; off += PPB) {
        __syncthreads();   // sld ready (1st iter) / prev chunk done with srec
        if (t < PPB && off + (unsigned)t < n)
            srec[t] = rec[bs + off + (unsigned)t];
        __syncthreads();

        if (off + (unsigned)pl < n) {
            const vf4 r = srec[pl];
            const float qx = r.x, qy = r.y, qz = r.z;
            const int idx = __float_as_int(r.w);

            const float fx = floorf(qx), fy = floorf(qy), fz = floorf(qz);
            const float wx1 = qx - fx, wy1 = qy - fy, wz1 = qz - fz;
            const float wx0 = 1.0f - wx1, wy0 = 1.0f - wy1, wz0 = 1.0f - wz1;
            const int ix0 = min(max((int)fx, 0), RES - 1);
            const int ix1 = min(ix0 + 1, RES - 1);

            const int x18_0 = ix0 * 18 + 2 * f;
            const int x18_1 = ix1 * 18 + 2 * f;

            vf2   v[8];
            float w[8];
            #pragma unroll
            for (int k = 0; k < 8; ++k) {
                const int dx = k & 1, dy = (k >> 1) & 1, dz = k >> 2;
                const int cell = dy + 2 * dz;
                const int o = cell * ROWF + (dx ? x18_1 : x18_0);
                v[k] = *reinterpret_cast<const vf2*>(&sld[o]);
                w[k] = (dx ? wx1 : wx0) * (dy ? wy1 : wy0) * (dz ? wz1 : wz0);
            }

            float ax = 0.0f, ay = 0.0f;
            #pragma unroll
            for (int k = 0; k < 8; ++k) { ax += v[k].x * w[k]; ay += v[k].y * w[k]; }

            vf2 o2; o2.x = ax; o2.y = ay;
            __builtin_nontemporal_store(o2,
                reinterpret_cast<vf2*>(out + (size_t)idx * 18 + 2 * f));
        }
    }
}

// ---------------- R2 fallback (used only if workspace is too small) ----------
__global__ __launch_bounds__(TPB)
void dense_grid_trilerp(const float* __restrict__ pts,
                        const float* __restrict__ cb,
                        const float* __restrict__ tr,
                        float* __restrict__ out,
                        int npts)
{
    __shared__ float spts[PPB * 3];
    if (threadIdx.x < PPB * 3) {
        int g = blockIdx.x * (PPB * 3) + threadIdx.x;
        spts[threadIdx.x] = (g < npts * 3) ? __builtin_nontemporal_load(&pts[g]) : 0.0f;
    }
    __syncthreads();

    const int pl = threadIdx.x / 9;
    const int f  = threadIdx.x - pl * 9;
    const int p  = blockIdx.x * PPB + pl;
    if (p >= npts) return;

    const Xf X = load_xf(tr);
    const float x = spts[pl*3 + 0] - X.tx;
    const float y = spts[pl*3 + 1] - X.ty;
    const float z = spts[pl*3 + 2] - X.tz;
    const float qx = qcoord(X.m00, X.m01, X.m02, x, y, z);
    const float qy = qcoord(X.m10, X.m11, X.m12, x, y, z);
    const float qz = qcoord(X.m20, X.m21, X.m22, x, y, z);

    const float fx = floorf(qx), fy = floorf(qy), fz = floorf(qz);
    const float wx1 = qx - fx, wy1 = qy - fy, wz1 = qz - fz;
    const float wx0 = 1.0f - wx1, wy0 = 1.0f - wy1, wz0 = 1.0f - wz1;
    const int ix0 = min(max((int)fx, 0), RES - 1); const int ix1 = min(ix0 + 1, RES - 1);
    const int iy0 = min(max((int)fy, 0), RES - 1); const int iy1 = min(iy0 + 1, RES - 1);
    const int iz0 = min(max((int)fz, 0), RES - 1); const int iz1 = min(iz0 + 1, RES - 1);

    int   ro[8];
    float w[8];
    #pragma unroll
    for (int k = 0; k < 8; ++k) {
        const int dx = k & 1, dy = (k >> 1) & 1, dz = k >> 2;
        const int ix = dx ? ix1 : ix0;
        const int iy = dy ? iy1 : iy0;
        const int iz = dz ? iz1 : iz0;
        ro[k] = ix + (iy << 7) + (iz << 14);
        w[k]  = (dx ? wx1 : wx0) * (dy ? wy1 : wy0) * (dz ? wz1 : wz0);
    }

    const float* cbf = cb + 2 * f;
    vf2 v[8];
    #pragma unroll
    for (int k = 0; k < 8; ++k)
        v[k] = *reinterpret_cast<const vf2*>(cbf + ro[k] * 18);

    float ax = 0.0f, ay = 0.0f;
    #pragma unroll
    for (int k = 0; k < 8; ++k) { ax += v[k].x * w[k]; ay += v[k].y * w[k]; }

    vf2 o; o.x = ax; o.y = ay;
    __builtin_nontemporal_store(o, reinterpret_cast<vf2*>(out + p * 18 + 2 * f));
}

extern "C" void kernel_launch(void* const* d_in, const int* in_sizes, int n_in,
                              void* d_out, int out_size, void* d_ws, size_t ws_size,
                              hipStream_t stream) {
    const float* pts = (const float*)d_in[0];   // [4*524288, 3] f32
    const float* cb  = (const float*)d_in[1];   // [128^3, 18] f32
    const float* tr  = (const float*)d_in[2];   // [4,4] f32
    float* out = (float*)d_out;                 // [4*524288, 18] f32

    const int npts = in_sizes[0] / 3;

    const size_t meta  = (size_t)NB2 * 3 * sizeof(unsigned);      // 196608 B (256-aligned)
    const size_t need  = meta + (size_t)npts * 16 + 256;
    if (d_ws == nullptr || ws_size < need || npts <= 0) {
        const int blocks = (npts + PPB - 1) / PPB;
        dense_grid_trilerp<<<blocks, TPB, 0, stream>>>(pts, cb, tr, out, npts);
        return;
    }

    unsigned* hist   = (unsigned*)d_ws;
    unsigned* base   = hist + NB2;
    unsigned* cursor = base + NB2;
    vf4* rec = (vf4*)((char*)d_ws + ((meta + 255) / 256) * 256);

    const int pblocks = (npts + 255) / 256;
    k_zero<<<(NB2 + 255) / 256, 256, 0, stream>>>(hist);
    k_hist<<<pblocks, 256, 0, stream>>>(pts, tr, hist, npts);
    k_scan<<<1, 1024, 0, stream>>>(hist, base, cursor);
    k_scatter<<<pblocks, 256, 0, stream>>>(pts, tr, cursor, rec, npts);
    k_main<<<NB2, TPB, 0, stream>>>(rec, hist, base, cb, out);
}

// Round 3
// 506.567 us; speedup vs baseline: 1.2426x; 1.2426x over previous
//
#include <hip/hip_runtime.h>

// DenseGrid trilinear interpolation, MI355X.
// R5: two-level sort + strip-walking LDS-ring interpolation.
//  - Pass A: coarse 512-bin block-aggregated counting sort (R3-proven shape,
//    8192-pt chunks -> 256 B runs, minimal cross-block false sharing).
//  - Pass B: one block per coarse bin sub-sorts its ~4K recs IN LDS, IN PLACE
//    (block-exclusive range -> no cross-XCD write sharing), emitting exact
//    fine (iz0,iy0) order + per-fine-bin counts histF.
//  - k_main5: one block per coarse bin walks its 32 fine bins with a 4-slot
//    ring of y-row pairs in LDS (72 KB). One 18 KB row-pair staged per bin,
//    overlapped with compute. Bit-identical per-point math -> absmax unchanged.
// Fallback to the R2 single-kernel path if workspace is too small.

constexpr int RES  = 128;
constexpr int NBA  = 512;           // coarse bins: (iz0<<2)|(iy0>>5)
constexpr int TPM  = 576;           // main kernel: 9 threads/point, 64 pts/chunk
constexpr int PPB  = 64;
constexpr int ROWF = 128 * 18;      // floats per (y,z) codebook row
constexpr int SUB_CAP = 8160;       // LDS rec cache per coarse bin (mean 4096)

constexpr int HIST_CHUNK = 1024;
constexpr int SCAT_CHUNK = 8192;

typedef float vf2 __attribute__((ext_vector_type(2)));
typedef float vf4 __attribute__((ext_vector_type(4)));

struct Xf {
    float m00, m01, m02, m10, m11, m12, m20, m21, m22;
    float tx, ty, tz;
};

__device__ __forceinline__ Xf load_xf(const float* __restrict__ tr) {
    Xf X;
    const float a = tr[0], b = tr[1],  c = tr[2];
    const float d = tr[4], e = tr[5],  g = tr[6];
    const float h = tr[8], i = tr[9],  j = tr[10];
    X.tx = tr[3]; X.ty = tr[7]; X.tz = tr[11];
    const float det = a*(e*j - g*i) - b*(d*j - g*h) + c*(d*i - e*h);
    const float rd  = 1.0f / det;
    X.m00 = (e*j - g*i) * rd; X.m01 = (c*i - b*j) * rd; X.m02 = (b*g - c*e) * rd;
    X.m10 = (g*h - d*j) * rd; X.m11 = (a*j - c*h) * rd; X.m12 = (c*d - a*g) * rd;
    X.m20 = (d*i - e*h) * rd; X.m21 = (b*h - a*i) * rd; X.m22 = (a*e - b*d) * rd;
    return X;
}

// Explicit fma chain: identical across all kernels (bin assignment must match).
__device__ __forceinline__ float qcoord(float m0, float m1, float m2,
                                        float x, float y, float z) {
    return __fmaf_rn(m0, x, __fmaf_rn(m1, y, m2 * z)) * (float)(RES - 1);
}

__device__ __forceinline__ int clamp_idx(float q) {
    return min(max((int)floorf(q), 0), RES - 1);
}

__device__ __forceinline__ int coarse_key(float qy, float qz) {
    return (clamp_idx(qz) << 2) | (clamp_idx(qy) >> 5);
}

// ---------------------------------------------------------------- pass A ----
__global__ __launch_bounds__(256)
void k_zero(unsigned* __restrict__ histA) {
    const int i = blockIdx.x * 256 + threadIdx.x;
    if (i < NBA) histA[i] = 0u;
}

__global__ __launch_bounds__(256)
void k_histA(const float* __restrict__ pts, const float* __restrict__ tr,
             unsigned* __restrict__ histA, int npts)
{
    __shared__ unsigned sh[NBA];
    const int t = threadIdx.x;
    for (int b = t; b < NBA; b += 256) sh[b] = 0u;
    __syncthreads();
    const Xf X = load_xf(tr);
    const int base = blockIdx.x * HIST_CHUNK;
    #pragma unroll
    for (int i = 0; i < HIST_CHUNK / 256; ++i) {
        const int p = base + t + i * 256;
        if (p < npts) {
            const float x = pts[p*3 + 0] - X.tx;
            const float y = pts[p*3 + 1] - X.ty;
            const float z = pts[p*3 + 2] - X.tz;
            const float qy = qcoord(X.m10, X.m11, X.m12, x, y, z);
            const float qz = qcoord(X.m20, X.m21, X.m22, x, y, z);
            atomicAdd(&sh[coarse_key(qy, qz)], 1u);
        }
    }
    __syncthreads();
    for (int b = t; b < NBA; b += 256) {
        const unsigned c = sh[b];
        if (c) atomicAdd(&histA[b], c);
    }
}

__global__ __launch_bounds__(NBA)
void k_scanA(const unsigned* __restrict__ histA,
             unsigned* __restrict__ baseA, unsigned* __restrict__ cursorA)
{
    __shared__ unsigned s[NBA];
    const int t = threadIdx.x;
    const unsigned my = histA[t];
    s[t] = my;
    __syncthreads();
    for (int off = 1; off < NBA; off <<= 1) {
        const unsigned v = (t >= off) ? s[t - off] : 0u;
        __syncthreads();
        s[t] += v;
        __syncthreads();
    }
    baseA[t]   = s[t] - my;
    cursorA[t] = s[t] - my;
}

__global__ __launch_bounds__(256)
void k_scatA(const float* __restrict__ pts, const float* __restrict__ tr,
             unsigned* __restrict__ cursorA, vf4* __restrict__ rec, int npts)
{
    __shared__ unsigned shist[NBA], sbase[NBA], scur[NBA];
    const int t = threadIdx.x;
    for (int b = t; b < NBA; b += 256) { shist[b] = 0u; scur[b] = 0u; }
    __syncthreads();
    const Xf X = load_xf(tr);
    const int base = blockIdx.x * SCAT_CHUNK;
    #pragma unroll
    for (int i = 0; i < SCAT_CHUNK / 256; ++i) {
        const int p = base + t + i * 256;
        if (p < npts) {
            const float x = pts[p*3 + 0] - X.tx;
            const float y = pts[p*3 + 1] - X.ty;
            const float z = pts[p*3 + 2] - X.tz;
            const float qy = qcoord(X.m10, X.m11, X.m12, x, y, z);
            const float qz = qcoord(X.m20, X.m21, X.m22, x, y, z);
            atomicAdd(&shist[coarse_key(qy, qz)], 1u);
        }
    }
    __syncthreads();
    for (int b = t; b < NBA; b += 256)
        sbase[b] = shist[b] ? atomicAdd(&cursorA[b], shist[b]) : 0u;
    __syncthreads();
    #pragma unroll
    for (int i = 0; i < SCAT_CHUNK / 256; ++i) {
        const int p = base + t + i * 256;
        if (p < npts) {
            const float x = pts[p*3 + 0] - X.tx;
            const float y = pts[p*3 + 1] - X.ty;
            const float z = pts[p*3 + 2] - X.tz;
            const float qx = qcoord(X.m00, X.m01, X.m02, x, y, z);
            const float qy = qcoord(X.m10, X.m11, X.m12, x, y, z);
            const float qz = qcoord(X.m20, X.m21, X.m22, x, y, z);
            const int bn = coarse_key(qy, qz);
            const unsigned r = atomicAdd(&scur[bn], 1u);
            unsigned pos = sbase[bn] + r;
            if (pos >= (unsigned)npts) pos = (unsigned)npts - 1u;  // insurance
            vf4 v; v.x = qx; v.y = qy; v.z = qz; v.w = __int_as_float(p);
            rec[pos] = v;
        }
    }
}

// ---------------------------------------------------------------- pass B ----
// One block per coarse bin: in-LDS, in-place sub-sort to fine (iy0) order.
__global__ __launch_bounds__(1024)
void k_subsort(vf4* __restrict__ rec, const unsigned* __restrict__ histA,
               const unsigned* __restrict__ baseA, unsigned* __restrict__ histF)
{
    const int cbn = blockIdx.x;
    const int t = threadIdx.x;
    const unsigned n = histA[cbn];
    const unsigned b0 = baseA[cbn];
    const int iz0 = cbn >> 2;
    const int ybase = (cbn & 3) << 5;
    const int bf = (iz0 << 7) | ybase;

    if (n == 0u) { if (t < 32) histF[bf + t] = 0u; return; }
    if (n > (unsigned)SUB_CAP) {    // ~60 sigma out; k_main5 handles flagged bins
        if (t < 32) histF[bf + t] = (t == 0) ? (n | 0x80000000u) : 0u;
        return;
    }

    __shared__ vf4 c[SUB_CAP];
    __shared__ unsigned h[32], cur[32];
    if (t < 32) h[t] = 0u;
    __syncthreads();

    for (unsigned i = t; i < n; i += 1024) {
        const vf4 v = rec[b0 + i];
        c[i] = v;
        const int key = min(max(clamp_idx(v.y) - ybase, 0), 31);
        atomicAdd(&h[key], 1u);
    }
    __syncthreads();
    if (t == 0) {
        unsigned run = 0u;
        for (int k = 0; k < 32; ++k) { cur[k] = run; run += h[k]; }
    }
    __syncthreads();
    for (unsigned i = t; i < n; i += 1024) {
        const vf4 v = c[i];
        const int key = min(max(clamp_idx(v.y) - ybase, 0), 31);
        const unsigned pos = atomicAdd(&cur[key], 1u);
        rec[b0 + pos] = v;          // block-exclusive range: no false sharing
    }
    if (t < 32) histF[bf + t] = h[t];
}

// ---------------------------------------------------------------- k_main ----
__global__ __launch_bounds__(TPM)
void k_main5(const vf4* __restrict__ rec, const unsigned* __restrict__ histF,
             const unsigned* __restrict__ baseA, const float* __restrict__ cbk,
             float* __restrict__ out)
{
    const int blk = blockIdx.x;           // coarse bin
    const int iz0 = blk >> 2;
    const int ybase = (blk & 3) << 5;
    const int t = threadIdx.x;
    const int pl = t / 9;
    const int f  = t - pl * 9;

    __shared__ float sld[4][2][ROWF];     // 4 y-slots x 2 z x 9216 B = 72 KB

    const unsigned bs = baseA[blk];
    const unsigned nj0raw = histF[(iz0 << 7) | ybase];

    auto stage = [&](int yn) {            // stage y-row pair into slot yn&3
        const int yc = min(yn, RES - 1);
        const int s  = yn & 3;
        #pragma unroll
        for (int zz = 0; zz < 2; ++zz) {
            const int zc = min(iz0 + zz, RES - 1);
            const vf2* __restrict__ src =
                reinterpret_cast<const vf2*>(cbk + (size_t)((zc << 14) | (yc << 7)) * 18);
            vf2* dst = reinterpret_cast<vf2*>(&sld[s][zz][0]);
            dst[t]       = src[t];
            dst[t + TPM] = src[t + TPM];
        }
    };

    if (nj0raw & 0x80000000u) {
        // Overflowed coarse bin (never expected): global-gather path.
        const unsigned n = nj0raw & 0x7fffffffu;
        for (unsigned off = 0; off < n; off += PPB) {
            const unsigned pi = off + (unsigned)pl;
            if (pi < n) {
                const vf4 r = rec[bs + pi];
                const float qx = r.x, qy = r.y, qz = r.z;
                const int idx = __float_as_int(r.w);
                const float fx = floorf(qx), fy = floorf(qy), fz = floorf(qz);
                const float wx1 = qx - fx, wy1 = qy - fy, wz1 = qz - fz;
                const float wx0 = 1.0f - wx1, wy0 = 1.0f - wy1, wz0 = 1.0f - wz1;
                const int ix0 = clamp_idx(qx), ix1 = min(ix0 + 1, RES - 1);
                const int iy0 = clamp_idx(qy), iy1 = min(iy0 + 1, RES - 1);
                const int izp = clamp_idx(qz), iz1 = min(izp + 1, RES - 1);
                vf2 v[8]; float w[8];
                #pragma unroll
                for (int k = 0; k < 8; ++k) {
                    const int dx = k & 1, dy = (k >> 1) & 1, dz = k >> 2;
                    const int ro = (dx ? ix1 : ix0) + ((dy ? iy1 : iy0) << 7)
                                 + ((dz ? iz1 : izp) << 14);
                    v[k] = *reinterpret_cast<const vf2*>(cbk + (size_t)ro * 18 + 2 * f);
                    w[k] = (dx ? wx1 : wx0) * (dy ? wy1 : wy0) * (dz ? wz1 : wz0);
                }
                float ax = 0.0f, ay = 0.0f;
                #pragma unroll
                for (int k = 0; k < 8; ++k) { ax += v[k].x * w[k]; ay += v[k].y * w[k]; }
                vf2 o; o.x = ax; o.y = ay;
                __builtin_nontemporal_store(o,
                    reinterpret_cast<vf2*>(out + (size_t)idx * 18 + 2 * f));
            }
        }
        return;
    }

    stage(ybase);
    stage(ybase + 1);
    unsigned cur = bs;
    __syncthreads();

    for (int j = 0; j < 32; ++j) {
        const int iy0 = ybase + j;
        const unsigned nj = histF[(iz0 << 7) | iy0];
        if (j < 31) stage(iy0 + 2);       // overlap next row pair with compute

        const int sy0 = iy0 & 3, sy1 = (iy0 + 1) & 3;
        for (unsigned off = 0; off < nj; off += PPB) {
            const unsigned pi = off + (unsigned)pl;
            if (pi < nj) {
                const vf4 r = __builtin_nontemporal_load(&rec[cur + pi]);
                const float qx = r.x, qy = r.y, qz = r.z;
                const int idx = __float_as_int(r.w);
                const float fx = floorf(qx), fy = floorf(qy), fz = floorf(qz);
                const float wx1 = qx - fx, wy1 = qy - fy, wz1 = qz - fz;
                const float wx0 = 1.0f - wx1, wy0 = 1.0f - wy1, wz0 = 1.0f - wz1;
                const int ix0 = clamp_idx(qx), ix1 = min(ix0 + 1, RES - 1);
                const int x0 = ix0 * 18 + 2 * f, x1 = ix1 * 18 + 2 * f;
                vf2 v[8]; float w[8];
                #pragma unroll
                for (int k = 0; k < 8; ++k) {
                    const int dx = k & 1, dy = (k >> 1) & 1, dz = k >> 2;
                    const float* base_ = &sld[dy ? sy1 : sy0][dz][0];
                    v[k] = *reinterpret_cast<const vf2*>(&base_[dx ? x1 : x0]);
                    w[k] = (dx ? wx1 : wx0) * (dy ? wy1 : wy0) * (dz ? wz1 : wz0);
                }
                float ax = 0.0f, ay = 0.0f;
                #pragma unroll
                for (int k = 0; k < 8; ++k) { ax += v[k].x * w[k]; ay += v[k].y * w[k]; }
                vf2 o; o.x = ax; o.y = ay;
                __builtin_nontemporal_store(o,
                    reinterpret_cast<vf2*>(out + (size_t)idx * 18 + 2 * f));
            }
        }
        cur += nj;
        __syncthreads();                  // stage visible; slot reuse safe
    }
}

// ---------------- R2 fallback (used only if workspace is too small) ----------
__global__ __launch_bounds__(TPM)
void dense_grid_trilerp(const float* __restrict__ pts,
                        const float* __restrict__ cb,
                        const float* __restrict__ tr,
                        float* __restrict__ out,
                        int npts)
{
    __shared__ float spts[PPB * 3];
    if (threadIdx.x < PPB * 3) {
        int g = blockIdx.x * (PPB * 3) + threadIdx.x;
        spts[threadIdx.x] = (g < npts * 3) ? __builtin_nontemporal_load(&pts[g]) : 0.0f;
    }
    __syncthreads();

    const int pl = threadIdx.x / 9;
    const int f  = threadIdx.x - pl * 9;
    const int p  = blockIdx.x * PPB + pl;
    if (p >= npts) return;

    const Xf X = load_xf(tr);
    const float x = spts[pl*3 + 0] - X.tx;
    const float y = spts[pl*3 + 1] - X.ty;
    const float z = spts[pl*3 + 2] - X.tz;
    const float qx = qcoord(X.m00, X.m01, X.m02, x, y, z);
    const float qy = qcoord(X.m10, X.m11, X.m12, x, y, z);
    const float qz = qcoord(X.m20, X.m21, X.m22, x, y, z);

    const float fx = floorf(qx), fy = floorf(qy), fz = floorf(qz);
    const float wx1 = qx - fx, wy1 = qy - fy, wz1 = qz - fz;
    const float wx0 = 1.0f - wx1, wy0 = 1.0f - wy1, wz0 = 1.0f - wz1;
    const int ix0 = clamp_idx(qx); const int ix1 = min(ix0 + 1, RES - 1);
    const int iy0 = clamp_idx(qy); const int iy1 = min(iy0 + 1, RES - 1);
    const int iz0 = clamp_idx(qz); const int iz1 = min(iz0 + 1, RES - 1);

    int   ro[8];
    float w[8];
    #pragma unroll
    for (int k = 0; k < 8; ++k) {
        const int dx = k & 1, dy = (k >> 1) & 1, dz = k >> 2;
        ro[k] = (dx ? ix1 : ix0) + ((dy ? iy1 : iy0) << 7) + ((dz ? iz1 : iz0) << 14);
        w[k]  = (dx ? wx1 : wx0) * (dy ? wy1 : wy0) * (dz ? wz1 : wz0);
    }

    const float* cbf = cb + 2 * f;
    vf2 v[8];
    #pragma unroll
    for (int k = 0; k < 8; ++k)
        v[k] = *reinterpret_cast<const vf2*>(cbf + ro[k] * 18);

    float ax = 0.0f, ay = 0.0f;
    #pragma unroll
    for (int k = 0; k < 8; ++k) { ax += v[k].x * w[k]; ay += v[k].y * w[k]; }

    vf2 o; o.x = ax; o.y = ay;
    __builtin_nontemporal_store(o, reinterpret_cast<vf2*>(out + p * 18 + 2 * f));
}

extern "C" void kernel_launch(void* const* d_in, const int* in_sizes, int n_in,
                              void* d_out, int out_size, void* d_ws, size_t ws_size,
                              hipStream_t stream) {
    const float* pts = (const float*)d_in[0];   // [4*524288, 3] f32
    const float* cb  = (const float*)d_in[1];   // [128^3, 18] f32
    const float* tr  = (const float*)d_in[2];   // [4,4] f32
    float* out = (float*)d_out;                 // [4*524288, 18] f32

    const int npts = in_sizes[0] / 3;

    // meta: histA(512) baseA(512) cursorA(512) histF(16384) = 71680 B (256-aligned)
    const size_t meta = (size_t)(NBA * 3 + 16384) * sizeof(unsigned);
    const size_t need = meta + (size_t)npts * 16;
    if (d_ws == nullptr || ws_size < need || npts <= 0) {
        const int blocks = (npts + PPB - 1) / PPB;
        dense_grid_trilerp<<<blocks, TPM, 0, stream>>>(pts, cb, tr, out, npts);
        return;
    }

    unsigned* histA   = (unsigned*)d_ws;
    unsigned* baseA   = histA + NBA;
    unsigned* cursorA = baseA + NBA;
    unsigned* histF   = cursorA + NBA;
    vf4* rec = (vf4*)((char*)d_ws + meta);

    k_zero<<<(NBA + 255) / 256, 256, 0, stream>>>(histA);
    k_histA<<<(npts + HIST_CHUNK - 1) / HIST_CHUNK, 256, 0, stream>>>(pts, tr, histA, npts);
    k_scanA<<<1, NBA, 0, stream>>>(histA, baseA, cursorA);
    k_scatA<<<(npts + SCAT_CHUNK - 1) / SCAT_CHUNK, 256, 0, stream>>>(pts, tr, cursorA, rec, npts);
    k_subsort<<<NBA, 1024, 0, stream>>>(rec, histA, baseA, histF);
    k_main5<<<NBA, TPM, 0, stream>>>(rec, histF, baseA, cb, out);
}